// Round 4
// baseline (392.116 us; speedup 1.0000x reference)
//
#include <hip/hip_runtime.h>
#include <math.h>

static constexpr int B_ = 8, C_ = 512, T_ = 2048, C3_ = 1536;
static constexpr float INV_TEMP = 1.0f / 0.07f;

typedef __attribute__((ext_vector_type(8))) short short8;
typedef __attribute__((ext_vector_type(4))) float floatx4;

__device__ __forceinline__ float b2f(unsigned short u) {
  union { unsigned int i; float f; } v; v.i = ((unsigned int)u) << 16; return v.f;
}
__device__ __forceinline__ unsigned short f2b(float f) {
  union { float f; unsigned int i; } v; v.f = f;
  const unsigned int x = v.i;
  return (unsigned short)((x + 0x7FFFu + ((x >> 16) & 1u)) >> 16);
}
__device__ __forceinline__ void gld16(const unsigned short* g, unsigned short* l) {
  __builtin_amdgcn_global_load_lds(
      (const __attribute__((address_space(1))) void*)g,
      (__attribute__((address_space(3))) void*)l, 16, 0, 0);
}

// ---------------------------------------------------------------------------
// TN-form bf16 MFMA GEMM: C[m,n] = sum_k A[m,k]*B[n,k], A:[M,K] B:[N,K],
// both k-contiguous bf16. 128xTN tile (TN=128 or 64), BK=32, 256 thr =
// 4 waves (2x2, wave-tile 64 x TN/2), 16x16x32 MFMA.
// 3-deep LDS ring with inline-asm `s_waitcnt vmcnt(NL); s_barrier` so the
// next tile's loads stay IN FLIGHT across the barrier (no vmcnt(0) drain —
// the m97-structure stall). stage(i+2) is issued after barrier(i), so the
// buffer it writes ((i+2)%3 == (i-1)%3) was last read in compute(i-1),
// which every wave finished before barrier(i): WAR-safe.
// XOR granule swizzle keeps LDS bank aliasing <= 2-way (free).
// ---------------------------------------------------------------------------
template<int TN, bool OUT_BF16, bool EPI>
__global__ __launch_bounds__(256)
void gemm_tn(const unsigned short* __restrict__ A, const unsigned short* __restrict__ B,
             void* __restrict__ Cout, int K, int lda, int ldb, int ldc,
             long long sA, long long sB, long long sC,
             const float* __restrict__ rs, const float* __restrict__ cs,
             int rcStride, float scale)
{
  constexpr int NW = TN / 2;        // wave n-extent (64 or 32)
  constexpr int NF = NW / 16;       // B fragments per wave (4 or 2)
  constexpr int NL = 2 + TN / 64;   // gld16 per wave per tile (4 or 3)

  const int bz = blockIdx.z;
  A += (long long)bz * sA;
  B += (long long)bz * sB;
  if (EPI) { rs += (long long)bz * rcStride; cs += (long long)bz * rcStride; }
  const int m0 = blockIdx.y * 128, n0 = blockIdx.x * TN;
  const int tid = threadIdx.x;
  const int w = tid >> 6, lane = tid & 63;
  const int wm = (w >> 1) * 64, wn = (w & 1) * NW;
  const int rl = lane & 15, qd = lane >> 4;

  __shared__ __align__(16) unsigned short As[3][128 * 32];
  __shared__ __align__(16) unsigned short Bs[3][TN * 32];

  // staging: lane -> (row sr, granule slot sg); global granule XOR-swizzled
  const int sr = lane >> 2, sg = lane & 3;
  const int aml0 = 32 * w + sr, aml1 = aml0 + 16;
  const int aq0 = sg ^ ((aml0 >> 1) & 3), aq1 = sg ^ ((aml1 >> 1) & 3);
  const unsigned short* gA0 = A + (long long)(m0 + aml0) * lda + aq0 * 8;
  const unsigned short* gA1 = A + (long long)(m0 + aml1) * lda + aq1 * 8;
  const int bml0 = (TN == 128 ? 32 * w : 16 * w) + sr, bml1 = bml0 + 16;
  const int bq0 = sg ^ ((bml0 >> 1) & 3), bq1 = sg ^ ((bml1 >> 1) & 3);
  const unsigned short* gB0 = B + (long long)(n0 + bml0) * ldb + bq0 * 8;
  const unsigned short* gB1 = B + (long long)(n0 + bml1) * ldb + bq1 * 8;

  // fragment read offsets (swizzle-corrected)
  int aoff[4], boff[NF];
  #pragma unroll
  for (int i = 0; i < 4; ++i) {
    const int mr = wm + i * 16 + rl;
    aoff[i] = mr * 32 + ((qd ^ ((mr >> 1) & 3)) * 8);
  }
  #pragma unroll
  for (int j = 0; j < NF; ++j) {
    const int nr = wn + j * 16 + rl;
    boff[j] = nr * 32 + ((qd ^ ((nr >> 1) & 3)) * 8);
  }

  floatx4 acc[4][NF];
  #pragma unroll
  for (int i = 0; i < 4; ++i)
    #pragma unroll
    for (int j = 0; j < NF; ++j) acc[i][j] = 0.0f;

  auto stage = [&](int t, int bf) {
    const int ko = t * 32;
    gld16(gA0 + ko, As[bf] + (32 * w) * 32);
    gld16(gA1 + ko, As[bf] + (32 * w + 16) * 32);
    if (TN == 128) {
      gld16(gB0 + ko, Bs[bf] + (32 * w) * 32);
      gld16(gB1 + ko, Bs[bf] + (32 * w + 16) * 32);
    } else {
      gld16(gB0 + ko, Bs[bf] + (16 * w) * 32);
    }
  };
  auto compute = [&](int bf) {
    short8 fa[4], fb[NF];
    #pragma unroll
    for (int i = 0; i < 4; ++i) fa[i] = *(const short8*)(As[bf] + aoff[i]);
    #pragma unroll
    for (int j = 0; j < NF; ++j) fb[j] = *(const short8*)(Bs[bf] + boff[j]);
    #pragma unroll
    for (int i = 0; i < 4; ++i)
      #pragma unroll
      for (int j = 0; j < NF; ++j)
        acc[i][j] = __builtin_amdgcn_mfma_f32_16x16x32_bf16(fa[i], fb[j], acc[i][j], 0, 0, 0);
  };

  const int niter = K >> 5;
  stage(0, 0);
  stage(1, 1);
  int buf = 0;
  for (int i = 0; i < niter - 1; ++i) {
    // keep next tile's NL loads in flight; wait only for tile i's
    if (NL == 4) asm volatile("s_waitcnt vmcnt(4)\n\ts_barrier" ::: "memory");
    else         asm volatile("s_waitcnt vmcnt(3)\n\ts_barrier" ::: "memory");
    if (i + 2 < niter) {
      int nb = buf + 2; if (nb >= 3) nb -= 3;
      stage(i + 2, nb);
    }
    compute(buf);
    if (++buf == 3) buf = 0;
  }
  asm volatile("s_waitcnt vmcnt(0)\n\ts_barrier" ::: "memory");
  compute(buf);

  // epilogue: C/D layout col=lane&15, row=(lane>>4)*4+reg
  #pragma unroll
  for (int i = 0; i < 4; ++i) {
    #pragma unroll
    for (int r = 0; r < 4; ++r) {
      const int row = m0 + wm + i * 16 + qd * 4 + r;
      const float rowf = EPI ? rs[row] * scale : 0.f;
      #pragma unroll
      for (int j = 0; j < NF; ++j) {
        const int col = n0 + wn + j * 16 + rl;
        float v = acc[i][j][r];
        if (EPI) v *= rowf * cs[col];
        const long long idx = (long long)bz * sC + (long long)row * ldc + col;
        if (OUT_BF16) ((unsigned short*)Cout)[idx] = f2b(v);
        else          ((float*)Cout)[idx] = v;
      }
    }
  }
}

// ---------------------------------------------------------------------------
// x [B,C,T] fp32 -> xT [B,T,C] bf16 (transpose-convert, 32x32 LDS tiles)
// ---------------------------------------------------------------------------
__global__ __launch_bounds__(256)
void conv_xT(const float* __restrict__ x, unsigned short* __restrict__ xT)
{
  const int b = blockIdx.z, t0 = blockIdx.x * 32, c0 = blockIdx.y * 32;
  const int tx = threadIdx.x & 31, ty = threadIdx.x >> 5;
  __shared__ float tile[32][33];
  const float* src = x + (long long)b * C_ * T_;
  #pragma unroll
  for (int r = 0; r < 4; ++r)
    tile[ty + 8 * r][tx] = src[(long long)(c0 + ty + 8 * r) * T_ + t0 + tx];
  __syncthreads();
  unsigned short* dst = xT + (long long)b * T_ * C_;
  #pragma unroll
  for (int r = 0; r < 4; ++r)
    dst[(long long)(t0 + ty + 8 * r) * C_ + c0 + tx] = f2b(tile[tx][ty + 8 * r]);
}

__global__ __launch_bounds__(256)
void conv_bf(const float* __restrict__ in, unsigned short* __restrict__ out, int n)
{
  const int i = blockIdx.x * 256 + threadIdx.x;
  if (i < n) out[i] = f2b(in[i]);
}

// ---------------------------------------------------------------------------
// Depthwise-3 (zero pad) on v channels [2C,3C): bf16 in [B,3C,T] -> v [B,C,T]
// ---------------------------------------------------------------------------
__global__ __launch_bounds__(256)
void dw_v(const unsigned short* __restrict__ qkv, const float* __restrict__ wdw,
          unsigned short* __restrict__ vout)
{
  const long long idx = (long long)blockIdx.x * 256 + threadIdx.x;  // [B*C*T)
  const int t = (int)(idx % T_);
  const long long rem = idx / T_;
  const int c = (int)(rem % C_), b = (int)(rem / C_);
  const unsigned short* src = qkv + ((long long)(b * C3_ + 2 * C_ + c)) * T_;
  const float* wp = wdw + (2 * C_ + c) * 3;
  const float xm = (t > 0)      ? b2f(src[t - 1]) : 0.f;
  const float x0 = b2f(src[t]);
  const float xp = (t < T_ - 1) ? b2f(src[t + 1]) : 0.f;
  vout[(long long)(b * C_ + c) * T_ + t] = f2b(fmaf(wp[0], xm, fmaf(wp[1], x0, wp[2] * xp)));
}

// ---------------------------------------------------------------------------
// Depthwise-3 + transpose for q (p=0) / k (p=1): [B,3C,T] -> [B,T,C] bf16
// ---------------------------------------------------------------------------
__global__ __launch_bounds__(256)
void dw_qk_t(const unsigned short* __restrict__ qkv, const float* __restrict__ wdw,
             unsigned short* __restrict__ qT, unsigned short* __restrict__ kT)
{
  const int bz = blockIdx.z, b = bz >> 1, p = bz & 1;
  const int t0 = blockIdx.x * 32, c0 = blockIdx.y * 32;
  const int tx = threadIdx.x & 31, ty = threadIdx.x >> 5;
  __shared__ float tin[32][34];   // [c][t-1 .. t+32]
  __shared__ float tout[32][33];  // [t][c]
  const int chb = b * C3_ + p * C_;
  #pragma unroll
  for (int r = 0; r < 4; ++r) {
    const int cy = ty + 8 * r;
    const unsigned short* src = qkv + (long long)(chb + c0 + cy) * T_;
    int t = t0 - 1 + tx;
    tin[cy][tx] = (t >= 0 && t < T_) ? b2f(src[t]) : 0.f;
    if (tx < 2) {
      const int t2 = t0 + 31 + tx;
      tin[cy][32 + tx] = (t2 < T_) ? b2f(src[t2]) : 0.f;
    }
  }
  __syncthreads();
  #pragma unroll
  for (int r = 0; r < 4; ++r) {
    const int cy = ty + 8 * r;
    const float* wp = wdw + (long long)(p * C_ + c0 + cy) * 3;
    tout[tx][cy] = fmaf(wp[0], tin[cy][tx], fmaf(wp[1], tin[cy][tx + 1], wp[2] * tin[cy][tx + 2]));
  }
  __syncthreads();
  unsigned short* dst = (p == 0 ? qT : kT) + (long long)b * T_ * C_;
  #pragma unroll
  for (int r = 0; r < 4; ++r)
    dst[(long long)(t0 + ty + 8 * r) * C_ + c0 + tx] = f2b(tout[ty + 8 * r][tx]);
}

// ---------------------------------------------------------------------------
// Row L2-norm stats from bf16 [B*T, C] rows: inv = 1/max(||row||,eps)
// ---------------------------------------------------------------------------
__global__ __launch_bounds__(256)
void norms_k(const unsigned short* __restrict__ qT, const unsigned short* __restrict__ kT,
             float* __restrict__ inv_nq, float* __restrict__ inv_nk)
{
  const int wave = threadIdx.x >> 6, lane = threadIdx.x & 63;
  const long long row = (long long)blockIdx.x * 4 + wave;
  const unsigned short* src = (blockIdx.y == 0 ? qT : kT) + row * C_ + lane * 8;
  const uint4 u = *(const uint4*)src;
  float ss = 0.f;
  const unsigned int uu[4] = {u.x, u.y, u.z, u.w};
  #pragma unroll
  for (int i = 0; i < 4; ++i) {
    const float lo = b2f(uu[i] & 0xFFFF), hi = b2f(uu[i] >> 16);
    ss = fmaf(lo, lo, ss); ss = fmaf(hi, hi, ss);
  }
  #pragma unroll
  for (int m = 32; m; m >>= 1) ss += __shfl_xor(ss, m);
  if (lane == 0)
    (blockIdx.y == 0 ? inv_nq : inv_nk)[row] = 1.f / fmaxf(sqrtf(ss), 1e-12f);
}

// ---------------------------------------------------------------------------
// Row softmax: fp32 [rows, T] -> bf16 [rows, T]. 256 thr, 8 elems/thread.
// ---------------------------------------------------------------------------
__global__ __launch_bounds__(256)
void softmax_bf(const float* __restrict__ S, unsigned short* __restrict__ P)
{
  const float* src = S + (long long)blockIdx.x * T_;
  unsigned short* dst = P + (long long)blockIdx.x * T_;
  const int tid = threadIdx.x;
  __shared__ float red[256];
  const float4 v0 = ((const float4*)src)[tid * 2];
  const float4 v1 = ((const float4*)src)[tid * 2 + 1];
  float vals[8] = {v0.x, v0.y, v0.z, v0.w, v1.x, v1.y, v1.z, v1.w};
  float mx = vals[0];
  #pragma unroll
  for (int i = 1; i < 8; ++i) mx = fmaxf(mx, vals[i]);
  red[tid] = mx; __syncthreads();
  for (int s = 128; s > 0; s >>= 1) {
    if (tid < s) red[tid] = fmaxf(red[tid], red[tid + s]);
    __syncthreads();
  }
  mx = red[0]; __syncthreads();
  float sum = 0.f;
  #pragma unroll
  for (int i = 0; i < 8; ++i) { vals[i] = __expf(vals[i] - mx); sum += vals[i]; }
  red[tid] = sum; __syncthreads();
  for (int s = 128; s > 0; s >>= 1) {
    if (tid < s) red[tid] += red[tid + s];
    __syncthreads();
  }
  const float inv = 1.f / red[0];
  unsigned short o[8];
  #pragma unroll
  for (int i = 0; i < 8; ++i) o[i] = f2b(vals[i] * inv);
  uint4 pk;
  pk.x = (unsigned int)o[0] | ((unsigned int)o[1] << 16);
  pk.y = (unsigned int)o[2] | ((unsigned int)o[3] << 16);
  pk.z = (unsigned int)o[4] | ((unsigned int)o[5] << 16);
  pk.w = (unsigned int)o[6] | ((unsigned int)o[7] << 16);
  ((uint4*)dst)[tid] = pk;
}

// ---------------------------------------------------------------------------
// Workspace arena (bytes), total ~185.1 MB (layout unchanged from R2).
// ---------------------------------------------------------------------------
extern "C" void kernel_launch(void* const* d_in, const int* in_sizes, int n_in,
                              void* d_out, int out_size, void* d_ws, size_t ws_size,
                              hipStream_t stream)
{
  const float* x      = (const float*)d_in[0];
  const float* w_qkv  = (const float*)d_in[1];
  const float* w_dw   = (const float*)d_in[2];
  const float* w_proj = (const float*)d_in[3];
  float* out = (float*)d_out;

  char* base = (char*)d_ws;
  float*          scores  = (float*)base;
  unsigned short* xT      = (unsigned short*)base;                    // alias
  unsigned short* wqkv_bf = (unsigned short*)(base + 16777216);       // alias
  unsigned short* av_t    = (unsigned short*)base;                    // alias (late)
  char* p = base + 67108864;
  unsigned short* qT = (unsigned short*)p; p += 16777216;
  unsigned short* kT = (unsigned short*)p; p += 16777216;
  unsigned short* vb = (unsigned short*)p; p += 16777216;
  unsigned short* attn    = (unsigned short*)p;
  unsigned short* qkv_bf  = (unsigned short*)p;                       // alias (early)
  p += 67108864;
  unsigned short* wproj_bf = (unsigned short*)p; p += 524288;
  float* inv_nq = (float*)p; p += 65536;
  float* inv_nk = (float*)p;

  const long long TC = (long long)T_ * C_, TT = (long long)T_ * T_;

  // 0) conversions
  conv_xT<<<dim3(T_ / 32, C_ / 32, B_), 256, 0, stream>>>(x, xT);
  conv_bf<<<(C3_ * C_) / 256, 256, 0, stream>>>(w_qkv, wqkv_bf, C3_ * C_);
  conv_bf<<<(C_ * C_) / 256, 256, 0, stream>>>(w_proj, wproj_bf, C_ * C_);

  // 1) qkv[b][o][t] = sum_c wqkv[o][c] * x[c][t]
  gemm_tn<128, true, false><<<dim3(16, 12, B_), 256, 0, stream>>>(
      wqkv_bf, xT, qkv_bf, C_, C_, C_, T_,
      0LL, TC, (long long)C3_ * T_, nullptr, nullptr, 0, 1.f);

  // 2) depthwise conv
  dw_v<<<(int)(((long long)B_ * C_ * T_) / 256), 256, 0, stream>>>(qkv_bf, w_dw, vb);
  dw_qk_t<<<dim3(T_ / 32, C_ / 32, B_ * 2), 256, 0, stream>>>(qkv_bf, w_dw, qT, kT);

  // 3) channel-L2 stats (from bf16 values — exact normalization of rounded vecs)
  norms_k<<<dim3((B_ * T_) / 4, 2), 256, 0, stream>>>(qT, kT, inv_nq, inv_nk);

  // 4) scores + softmax, two half-batches of 4 (scores buffer reused)
  for (int h = 0; h < 2; ++h) {
    const long long o = (long long)h * 4;
    gemm_tn<128, false, true><<<dim3(16, 16, 4), 256, 0, stream>>>(
        qT + o * TC, kT + o * TC, scores, C_, C_, C_, T_,
        TC, TC, TT, inv_nq + o * T_, inv_nk + o * T_, T_, INV_TEMP);
    softmax_bf<<<4 * T_, 256, 0, stream>>>(scores, attn + o * TT);
  }

  // 5) av_t[b][t][c] = sum_s attn[t][s] * v[c][s]  (TN=64 -> 1024 blocks)
  gemm_tn<64, true, false><<<dim3(8, 16, B_), 256, 0, stream>>>(
      attn, vb, av_t, T_, T_, T_, C_,
      TT, (long long)C_ * T_, TC, nullptr, nullptr, 0, 1.f);

  // 6) out[b][o][t] = sum_c wproj[o][c] * av_t[t][c]  (TN=64 -> 1024 blocks)
  gemm_tn<64, false, false><<<dim3(32, 4, B_), 256, 0, stream>>>(
      wproj_bf, av_t, out, C_, C_, C_, T_,
      0LL, TC, (long long)C_ * T_, nullptr, nullptr, 0, 1.f);
}

// Round 5
// 336.758 us; speedup vs baseline: 1.1644x; 1.1644x over previous
//
#include <hip/hip_runtime.h>
#include <math.h>

static constexpr int B_ = 8, C_ = 512, T_ = 2048, C3_ = 1536;
static constexpr float INV_TEMP = 1.0f / 0.07f;

typedef __attribute__((ext_vector_type(8))) short short8;
typedef __attribute__((ext_vector_type(4))) float floatx4;

__device__ __forceinline__ float b2f(unsigned short u) {
  union { unsigned int i; float f; } v; v.i = ((unsigned int)u) << 16; return v.f;
}
__device__ __forceinline__ unsigned short f2b(float f) {
  union { float f; unsigned int i; } v; v.f = f;
  const unsigned int x = v.i;
  return (unsigned short)((x + 0x7FFFu + ((x >> 16) & 1u)) >> 16);
}
__device__ __forceinline__ void gld16(const unsigned short* g, unsigned short* l) {
  __builtin_amdgcn_global_load_lds(
      (const __attribute__((address_space(1))) void*)g,
      (__attribute__((address_space(3))) void*)l, 16, 0, 0);
}

// ---------------------------------------------------------------------------
// TN-form bf16 MFMA GEMM: C[m,n] = sum_k A[m,k]*B[n,k], A:[M,K] B:[N,K],
// both k-contiguous bf16. 128x128 tile, BK=32, 256 thr = 4 waves (2x2 of
// 64x64), 16x16x32 MFMA. 3-deep LDS ring, `s_waitcnt vmcnt(NL); s_barrier`
// keeps the next tile's loads in flight across the barrier.
// MODE 0: plain store.
// MODE 2: softmax epilogue — s = acc*rs[row]*cs[col]*scale; p = exp(s-scale)
//         (scale = 1/TEMP = global max bound, so no row-max pass needed);
//         store bf16 p and atomically accumulate row sums of the ROUNDED p
//         into denom (weights later sum to exactly 1 after the row divide).
// MODE 3: row divide — v = acc / rs[row]  (denominator application in AV).
// ---------------------------------------------------------------------------
template<bool OUT_BF16, int MODE>
__global__ __launch_bounds__(256)
void gemm_tn(const unsigned short* __restrict__ A, const unsigned short* __restrict__ B,
             void* __restrict__ Cout, int K, int lda, int ldb, int ldc,
             long long sA, long long sB, long long sC,
             const float* __restrict__ rs, const float* __restrict__ cs,
             float* __restrict__ denom, int rcStride, float scale)
{
  constexpr int NL = 4;   // gld16 per wave per tile

  const int bz = blockIdx.z;
  A += (long long)bz * sA;
  B += (long long)bz * sB;
  if (MODE == 2) { rs += (long long)bz * rcStride; cs += (long long)bz * rcStride;
                   denom += (long long)bz * rcStride; }
  if (MODE == 3) { rs += (long long)bz * rcStride; }
  const int m0 = blockIdx.y * 128, n0 = blockIdx.x * 128;
  const int tid = threadIdx.x;
  const int w = tid >> 6, lane = tid & 63;
  const int wm = (w >> 1) * 64, wn = (w & 1) * 64;
  const int rl = lane & 15, qd = lane >> 4;

  __shared__ __align__(16) unsigned short As[3][128 * 32];
  __shared__ __align__(16) unsigned short Bs[3][128 * 32];

  // staging: lane -> (row sr, granule slot sg); global granule XOR-swizzled
  const int sr = lane >> 2, sg = lane & 3;
  const int ml0 = 32 * w + sr, ml1 = ml0 + 16;
  const int q0 = sg ^ ((ml0 >> 1) & 3), q1 = sg ^ ((ml1 >> 1) & 3);
  const unsigned short* gA0 = A + (long long)(m0 + ml0) * lda + q0 * 8;
  const unsigned short* gA1 = A + (long long)(m0 + ml1) * lda + q1 * 8;
  const unsigned short* gB0 = B + (long long)(n0 + ml0) * ldb + q0 * 8;
  const unsigned short* gB1 = B + (long long)(n0 + ml1) * ldb + q1 * 8;

  // fragment read offsets (swizzle-corrected)
  int aoff[4], boff[4];
  #pragma unroll
  for (int i = 0; i < 4; ++i) {
    const int mr = wm + i * 16 + rl;
    aoff[i] = mr * 32 + ((qd ^ ((mr >> 1) & 3)) * 8);
    const int nr = wn + i * 16 + rl;
    boff[i] = nr * 32 + ((qd ^ ((nr >> 1) & 3)) * 8);
  }

  floatx4 acc[4][4];
  #pragma unroll
  for (int i = 0; i < 4; ++i)
    #pragma unroll
    for (int j = 0; j < 4; ++j) acc[i][j] = 0.0f;

  auto stage = [&](int t, int bf) {
    const int ko = t * 32;
    gld16(gA0 + ko, As[bf] + (32 * w) * 32);
    gld16(gA1 + ko, As[bf] + (32 * w + 16) * 32);
    gld16(gB0 + ko, Bs[bf] + (32 * w) * 32);
    gld16(gB1 + ko, Bs[bf] + (32 * w + 16) * 32);
  };
  auto compute = [&](int bf) {
    short8 fa[4], fb[4];
    #pragma unroll
    for (int i = 0; i < 4; ++i) fa[i] = *(const short8*)(As[bf] + aoff[i]);
    #pragma unroll
    for (int j = 0; j < 4; ++j) fb[j] = *(const short8*)(Bs[bf] + boff[j]);
    #pragma unroll
    for (int i = 0; i < 4; ++i)
      #pragma unroll
      for (int j = 0; j < 4; ++j)
        acc[i][j] = __builtin_amdgcn_mfma_f32_16x16x32_bf16(fa[i], fb[j], acc[i][j], 0, 0, 0);
  };

  const int niter = K >> 5;
  stage(0, 0);
  stage(1, 1);
  int buf = 0;
  for (int i = 0; i < niter - 1; ++i) {
    asm volatile("s_waitcnt vmcnt(%0)\n\ts_barrier" :: "i"(NL) : "memory");
    if (i + 2 < niter) {
      int nb = buf + 2; if (nb >= 3) nb -= 3;
      stage(i + 2, nb);
    }
    compute(buf);
    if (++buf == 3) buf = 0;
  }
  asm volatile("s_waitcnt vmcnt(0)\n\ts_barrier" ::: "memory");
  compute(buf);

  // epilogue: C/D layout col=lane&15, row=(lane>>4)*4+reg
  #pragma unroll
  for (int i = 0; i < 4; ++i) {
    #pragma unroll
    for (int r = 0; r < 4; ++r) {
      const int row = m0 + wm + i * 16 + qd * 4 + r;
      float rowf = 0.f;
      if (MODE == 2) rowf = rs[row] * scale;
      if (MODE == 3) rowf = 1.0f / rs[row];
      float rsum = 0.f;
      #pragma unroll
      for (int j = 0; j < 4; ++j) {
        const int col = n0 + wn + j * 16 + rl;
        float v = acc[i][j][r];
        if (MODE == 2) {
          const float s = v * rowf * cs[col];
          const unsigned short pb = f2b(__expf(s - scale));
          rsum += b2f(pb);   // sum the ROUNDED weights
          ((unsigned short*)Cout)[(long long)bz * sC + (long long)row * ldc + col] = pb;
          continue;
        }
        if (MODE == 3) v *= rowf;
        const long long idx = (long long)bz * sC + (long long)row * ldc + col;
        if (OUT_BF16) ((unsigned short*)Cout)[idx] = f2b(v);
        else          ((float*)Cout)[idx] = v;
      }
      if (MODE == 2) {
        // reduce over the 16 rl lanes (xor masks < 16 stay within qd group)
        #pragma unroll
        for (int m = 1; m < 16; m <<= 1) rsum += __shfl_xor(rsum, m);
        if (rl == 0) atomicAdd(denom + row, rsum);
      }
    }
  }
}

__global__ __launch_bounds__(256)
void zero_f(float* __restrict__ p, int n)
{
  const int i = blockIdx.x * 256 + threadIdx.x;
  if (i < n) p[i] = 0.f;
}

// ---------------------------------------------------------------------------
// x [B,C,T] fp32 -> xT [B,T,C] bf16 (transpose-convert, 32x32 LDS tiles)
// ---------------------------------------------------------------------------
__global__ __launch_bounds__(256)
void conv_xT(const float* __restrict__ x, unsigned short* __restrict__ xT)
{
  const int b = blockIdx.z, t0 = blockIdx.x * 32, c0 = blockIdx.y * 32;
  const int tx = threadIdx.x & 31, ty = threadIdx.x >> 5;
  __shared__ float tile[32][33];
  const float* src = x + (long long)b * C_ * T_;
  #pragma unroll
  for (int r = 0; r < 4; ++r)
    tile[ty + 8 * r][tx] = src[(long long)(c0 + ty + 8 * r) * T_ + t0 + tx];
  __syncthreads();
  unsigned short* dst = xT + (long long)b * T_ * C_;
  #pragma unroll
  for (int r = 0; r < 4; ++r)
    dst[(long long)(t0 + ty + 8 * r) * C_ + c0 + tx] = f2b(tile[tx][ty + 8 * r]);
}

__global__ __launch_bounds__(256)
void conv_bf(const float* __restrict__ in, unsigned short* __restrict__ out, int n)
{
  const int i = blockIdx.x * 256 + threadIdx.x;
  if (i < n) out[i] = f2b(in[i]);
}

// ---------------------------------------------------------------------------
// Depthwise-3 (zero pad) on v channels [2C,3C): bf16 in [B,3C,T] -> v [B,C,T]
// ---------------------------------------------------------------------------
__global__ __launch_bounds__(256)
void dw_v(const unsigned short* __restrict__ qkv, const float* __restrict__ wdw,
          unsigned short* __restrict__ vout)
{
  const long long idx = (long long)blockIdx.x * 256 + threadIdx.x;  // [B*C*T)
  const int t = (int)(idx % T_);
  const long long rem = idx / T_;
  const int c = (int)(rem % C_), b = (int)(rem / C_);
  const unsigned short* src = qkv + ((long long)(b * C3_ + 2 * C_ + c)) * T_;
  const float* wp = wdw + (2 * C_ + c) * 3;
  const float xm = (t > 0)      ? b2f(src[t - 1]) : 0.f;
  const float x0 = b2f(src[t]);
  const float xp = (t < T_ - 1) ? b2f(src[t + 1]) : 0.f;
  vout[(long long)(b * C_ + c) * T_ + t] = f2b(fmaf(wp[0], xm, fmaf(wp[1], x0, wp[2] * xp)));
}

// ---------------------------------------------------------------------------
// Depthwise-3 + transpose for q (p=0) / k (p=1): [B,3C,T] -> [B,T,C] bf16
// ---------------------------------------------------------------------------
__global__ __launch_bounds__(256)
void dw_qk_t(const unsigned short* __restrict__ qkv, const float* __restrict__ wdw,
             unsigned short* __restrict__ qT, unsigned short* __restrict__ kT)
{
  const int bz = blockIdx.z, b = bz >> 1, p = bz & 1;
  const int t0 = blockIdx.x * 32, c0 = blockIdx.y * 32;
  const int tx = threadIdx.x & 31, ty = threadIdx.x >> 5;
  __shared__ float tin[32][34];   // [c][t-1 .. t+32]
  __shared__ float tout[32][33];  // [t][c]
  const int chb = b * C3_ + p * C_;
  #pragma unroll
  for (int r = 0; r < 4; ++r) {
    const int cy = ty + 8 * r;
    const unsigned short* src = qkv + (long long)(chb + c0 + cy) * T_;
    int t = t0 - 1 + tx;
    tin[cy][tx] = (t >= 0 && t < T_) ? b2f(src[t]) : 0.f;
    if (tx < 2) {
      const int t2 = t0 + 31 + tx;
      tin[cy][32 + tx] = (t2 < T_) ? b2f(src[t2]) : 0.f;
    }
  }
  __syncthreads();
  #pragma unroll
  for (int r = 0; r < 4; ++r) {
    const int cy = ty + 8 * r;
    const float* wp = wdw + (long long)(p * C_ + c0 + cy) * 3;
    tout[tx][cy] = fmaf(wp[0], tin[cy][tx], fmaf(wp[1], tin[cy][tx + 1], wp[2] * tin[cy][tx + 2]));
  }
  __syncthreads();
  unsigned short* dst = (p == 0 ? qT : kT) + (long long)b * T_ * C_;
  #pragma unroll
  for (int r = 0; r < 4; ++r)
    dst[(long long)(t0 + ty + 8 * r) * C_ + c0 + tx] = f2b(tout[ty + 8 * r][tx]);
}

// ---------------------------------------------------------------------------
// Row L2-norm stats from bf16 [B*T, C] rows: inv = 1/max(||row||,eps)
// ---------------------------------------------------------------------------
__global__ __launch_bounds__(256)
void norms_k(const unsigned short* __restrict__ qT, const unsigned short* __restrict__ kT,
             float* __restrict__ inv_nq, float* __restrict__ inv_nk)
{
  const int wave = threadIdx.x >> 6, lane = threadIdx.x & 63;
  const long long row = (long long)blockIdx.x * 4 + wave;
  const unsigned short* src = (blockIdx.y == 0 ? qT : kT) + row * C_ + lane * 8;
  const uint4 u = *(const uint4*)src;
  float ss = 0.f;
  const unsigned int uu[4] = {u.x, u.y, u.z, u.w};
  #pragma unroll
  for (int i = 0; i < 4; ++i) {
    const float lo = b2f(uu[i] & 0xFFFF), hi = b2f(uu[i] >> 16);
    ss = fmaf(lo, lo, ss); ss = fmaf(hi, hi, ss);
  }
  #pragma unroll
  for (int m = 32; m; m >>= 1) ss += __shfl_xor(ss, m);
  if (lane == 0)
    (blockIdx.y == 0 ? inv_nq : inv_nk)[row] = 1.f / fmaxf(sqrtf(ss), 1e-12f);
}

// ---------------------------------------------------------------------------
// Workspace arena (bytes), ~185.3 MB:
//  [0, 64M)    early: xT (16M) + wqkv_bf; late: av_t [B,T,C] bf16 (16M)
//  [64M,80M) qT  [80M,96M) kT  [96M,112M) vb
//  [112M,176M) attn bf16 [B,T,T] — early alias: qkv_bf (48M, dead after dw)
//  [176M,...)  wproj_bf, inv_nq, inv_nk, denom
// ---------------------------------------------------------------------------
extern "C" void kernel_launch(void* const* d_in, const int* in_sizes, int n_in,
                              void* d_out, int out_size, void* d_ws, size_t ws_size,
                              hipStream_t stream)
{
  const float* x      = (const float*)d_in[0];
  const float* w_qkv  = (const float*)d_in[1];
  const float* w_dw   = (const float*)d_in[2];
  const float* w_proj = (const float*)d_in[3];
  float* out = (float*)d_out;

  char* base = (char*)d_ws;
  unsigned short* xT      = (unsigned short*)base;                    // early
  unsigned short* wqkv_bf = (unsigned short*)(base + 16777216);       // early
  unsigned short* av_t    = (unsigned short*)base;                    // late
  char* p = base + 67108864;
  unsigned short* qT = (unsigned short*)p; p += 16777216;
  unsigned short* kT = (unsigned short*)p; p += 16777216;
  unsigned short* vb = (unsigned short*)p; p += 16777216;
  unsigned short* attn   = (unsigned short*)p;
  unsigned short* qkv_bf = (unsigned short*)p;                        // early alias
  p += 67108864;
  unsigned short* wproj_bf = (unsigned short*)p; p += 524288;
  float* inv_nq = (float*)p; p += 65536;
  float* inv_nk = (float*)p; p += 65536;
  float* denom  = (float*)p;

  const long long TC = (long long)T_ * C_, TT = (long long)T_ * T_;

  // 0) conversions + denom zero
  conv_xT<<<dim3(T_ / 32, C_ / 32, B_), 256, 0, stream>>>(x, xT);
  conv_bf<<<(C3_ * C_) / 256, 256, 0, stream>>>(w_qkv, wqkv_bf, C3_ * C_);
  conv_bf<<<(C_ * C_) / 256, 256, 0, stream>>>(w_proj, wproj_bf, C_ * C_);
  zero_f<<<(B_ * T_) / 256, 256, 0, stream>>>(denom, B_ * T_);

  // 1) qkv[b][o][t] = sum_c wqkv[o][c] * x[c][t]
  gemm_tn<true, 0><<<dim3(16, 12, B_), 256, 0, stream>>>(
      wqkv_bf, xT, qkv_bf, C_, C_, C_, T_,
      0LL, TC, (long long)C3_ * T_, nullptr, nullptr, nullptr, 0, 1.f);

  // 2) depthwise conv
  dw_v<<<(int)(((long long)B_ * C_ * T_) / 256), 256, 0, stream>>>(qkv_bf, w_dw, vb);
  dw_qk_t<<<dim3(T_ / 32, C_ / 32, B_ * 2), 256, 0, stream>>>(qkv_bf, w_dw, qT, kT);

  // 3) channel-L2 stats (from bf16 values)
  norms_k<<<dim3((B_ * T_) / 4, 2), 256, 0, stream>>>(qT, kT, inv_nq, inv_nk);

  // 4) scores + fused softmax (fixed-max exp) -> attn bf16 + denom atomics
  gemm_tn<true, 2><<<dim3(16, 16, B_), 256, 0, stream>>>(
      qT, kT, attn, C_, C_, C_, T_,
      TC, TC, TT, inv_nq, inv_nk, denom, T_, INV_TEMP);

  // 5) av_t[b][t][c] = (sum_s attn[t][s] * v[c][s]) / denom[t]
  gemm_tn<true, 3><<<dim3(4, 16, B_), 256, 0, stream>>>(
      attn, vb, av_t, T_, T_, T_, C_,
      TT, (long long)C_ * T_, TC, denom, nullptr, nullptr, T_, 1.f);

  // 6) out[b][o][t] = sum_c wproj[o][c] * av_t[t][c]
  gemm_tn<false, 0><<<dim3(16, 4, B_), 256, 0, stream>>>(
      wproj_bf, av_t, out, C_, C_, C_, T_,
      0LL, TC, (long long)C_ * T_, nullptr, nullptr, nullptr, 0, 1.f);
}